// Round 2
// baseline (521.948 us; speedup 1.0000x reference)
//
#include <hip/hip_runtime.h>
#include <hip/hip_bf16.h>

// Problem constants (B=1)
#define CC   448   // channels
#define CGC  64    // key/query channels = C/K
#define MMM  7     // m groups (C = MMM*CGC)
#define HWSZ 4096  // H*W = 64*64
#define KK2  49    // K*K
#define WID  64    // W
#define GPH  32    // geometry-prior hidden

// Scrambled-unfold address helper.
// Reference does unfold -> (C, K2, L) then .reshape(C, L, K2): element (c, l', t)
// maps to combined n = l'*49 + t, with p = n/4096 (window offset), l = n%4096 (spatial).
__device__ __forceinline__ int win_off(int n, bool& ok) {
    int p  = n >> 12;          // window tap index 0..48
    int l  = n & 4095;         // spatial index
    int di = (p * 37) >> 8;    // p / 7 (exact for 0..48)
    int dj = p - di * 7;       // p % 7
    int i  = (l >> 6) + di - 3;
    int j  = (l & 63) + dj - 3;
    ok = ((unsigned)i < 64u) & ((unsigned)j < 64u);
    return i * WID + j;
}

// ---------------- Kernel 1: km/qm = conv1x1(x, Wk/Wq) fused --------------
__global__ __launch_bounds__(256) void kq_kernel(
    const float* __restrict__ x,
    const float* __restrict__ Wk, const float* __restrict__ bk,
    const float* __restrict__ Wq, const float* __restrict__ bq,
    float* __restrict__ km, float* __restrict__ qm)
{
    __shared__ float wk_s[CC];
    __shared__ float wq_s[CC];
    const int g = blockIdx.y;
    const int l = blockIdx.x * 256 + threadIdx.x;
    for (int c = threadIdx.x; c < CC; c += 256) {
        wk_s[c] = Wk[g * CC + c];
        wq_s[c] = Wq[g * CC + c];
    }
    __syncthreads();
    float acck = 0.f, accq = 0.f;
    #pragma unroll 4
    for (int c = 0; c < CC; ++c) {
        float xv = x[c * HWSZ + l];
        acck = fmaf(wk_s[c], xv, acck);
        accq = fmaf(wq_s[c], xv, accq);
    }
    km[g * HWSZ + l] = acck + bk[g];
    qm[g * HWSZ + l] = accq + bq[g];
}

// ---------------- Kernel 2: geometry prior (64 x 49) ---------------------
__global__ __launch_bounds__(256) void gpk_kernel(
    const float* __restrict__ gw1, const float* __restrict__ gb1,
    const float* __restrict__ gw2, const float* __restrict__ gb2,
    float* __restrict__ gpk)
{
    const int idx = blockIdx.x * 256 + threadIdx.x;
    if (idx >= CGC * KK2) return;
    const int g = idx / KK2;
    const int t = idx - g * KK2;
    const int di = t / 7, dj = t - di * 7;
    const float xp = (float)(dj - 3);   // x_pos = ar[dj] = dj-3
    const float yp = (float)(3 - di);   // y_pos = ar[::-1][di] = 3-di
    float acc = gb2[g];
    #pragma unroll
    for (int j = 0; j < GPH; ++j) {
        float h = gw1[j * 2 + 0] * xp + gw1[j * 2 + 1] * yp + gb1[j];
        h = fmaxf(h, 0.f);
        acc = fmaf(gw2[g * GPH + j], h, acc);
    }
    gpk[idx] = acc;
}

// ---------------- Kernel 3: attention + aggregation ----------------------
// One thread per (g, l'). Row l' covers combined n = l'*49 + t.
__global__ __launch_bounds__(256) void attn_kernel(
    const float* __restrict__ km, const float* __restrict__ qm,
    const float* __restrict__ gpk, const float* __restrict__ x,
    float* __restrict__ pre)
{
    const int idx = blockIdx.x * 256 + threadIdx.x;  // 64*4096 threads
    const int g  = idx >> 12;       // uniform within a block (16 blocks per g)
    const int lp = idx & 4095;
    const int n0 = lp * KK2;

    // q center: scrambled element (g, l', CENTER=24)
    float qc;
    {
        bool ok;
        int off = win_off(n0 + 24, ok);
        qc = ok ? qm[g * HWSZ + off] : 0.f;
    }

    const float* __restrict__ kmg  = km + g * HWSZ;
    const float* __restrict__ gpkg = gpk + g * KK2;

    float a[KK2];
    float mx = -1e30f;
    #pragma unroll
    for (int t = 0; t < KK2; ++t) {
        bool ok;
        int off = win_off(n0 + t, ok);
        float kv = ok ? kmg[off] : 0.f;   // zero-padded taps still get gpk logit
        float av = fmaf(kv, qc, gpkg[t]);
        a[t] = av;
        mx = fmaxf(mx, av);
    }

    float d = 0.f;
    float acc[MMM] = {0.f, 0.f, 0.f, 0.f, 0.f, 0.f, 0.f};
    const float* __restrict__ xg = x + g * HWSZ;
    #pragma unroll
    for (int t = 0; t < KK2; ++t) {
        bool ok;
        int off = win_off(n0 + t, ok);
        float e = __expf(a[t] - mx);
        d += e;                            // padded taps count in denominator
        if (ok) {
            #pragma unroll
            for (int m = 0; m < MMM; ++m)
                acc[m] = fmaf(e, xg[m * CGC * HWSZ + off], acc[m]);
        }
    }
    const float inv = 1.f / d;
    #pragma unroll
    for (int m = 0; m < MMM; ++m)
        pre[(m * CGC + g) * HWSZ + lp] = acc[m] * inv;
}

// ---------------- Kernel 4: final conv1x1 448 -> 448 ---------------------
__global__ __launch_bounds__(256) void fconv_kernel(
    const float* __restrict__ pre,
    const float* __restrict__ Wf, const float* __restrict__ bfv,
    float* __restrict__ out)
{
    __shared__ float w_s[CC][8];   // c-major: per-c 8 output weights contiguous
    const int o0 = blockIdx.y * 8;
    const int l  = blockIdx.x * 256 + threadIdx.x;
    for (int i = threadIdx.x; i < 8 * CC; i += 256) {
        int oo = i & 7, c = i >> 3;
        w_s[c][oo] = Wf[(o0 + oo) * CC + c];
    }
    __syncthreads();
    float acc[8] = {0.f, 0.f, 0.f, 0.f, 0.f, 0.f, 0.f, 0.f};
    #pragma unroll 2
    for (int c = 0; c < CC; ++c) {
        float pv = pre[c * HWSZ + l];
        const float4* wp = (const float4*)&w_s[c][0];
        float4 w0 = wp[0];
        float4 w1 = wp[1];
        acc[0] = fmaf(w0.x, pv, acc[0]);
        acc[1] = fmaf(w0.y, pv, acc[1]);
        acc[2] = fmaf(w0.z, pv, acc[2]);
        acc[3] = fmaf(w0.w, pv, acc[3]);
        acc[4] = fmaf(w1.x, pv, acc[4]);
        acc[5] = fmaf(w1.y, pv, acc[5]);
        acc[6] = fmaf(w1.z, pv, acc[6]);
        acc[7] = fmaf(w1.w, pv, acc[7]);
    }
    #pragma unroll
    for (int oo = 0; oo < 8; ++oo)
        out[(o0 + oo) * HWSZ + l] = acc[oo] + bfv[o0 + oo];
}

extern "C" void kernel_launch(void* const* d_in, const int* in_sizes, int n_in,
                              void* d_out, int out_size, void* d_ws, size_t ws_size,
                              hipStream_t stream) {
    const float* x   = (const float*)d_in[0];
    const float* Wk  = (const float*)d_in[1];
    const float* bk  = (const float*)d_in[2];
    const float* Wq  = (const float*)d_in[3];
    const float* bq  = (const float*)d_in[4];
    const float* gw1 = (const float*)d_in[5];
    const float* gb1 = (const float*)d_in[6];
    const float* gw2 = (const float*)d_in[7];
    const float* gb2 = (const float*)d_in[8];
    const float* Wf  = (const float*)d_in[9];
    const float* bfv = (const float*)d_in[10];
    float* out = (float*)d_out;

    float* km  = (float*)d_ws;             // 64*4096
    float* qm  = km + CGC * HWSZ;          // 64*4096
    float* gpk = qm + CGC * HWSZ;          // 64*49 (3136, 16-aligned)
    float* pre = gpk + CGC * KK2;          // 448*4096

    kq_kernel  <<<dim3(16, CGC), 256, 0, stream>>>(x, Wk, bk, Wq, bq, km, qm);
    gpk_kernel <<<dim3(13),      256, 0, stream>>>(gw1, gb1, gw2, gb2, gpk);
    attn_kernel<<<dim3(1024),    256, 0, stream>>>(km, qm, gpk, x, pre);
    fconv_kernel<<<dim3(16, 56), 256, 0, stream>>>(pre, Wf, bfv, out);
}

// Round 3
// 261.716 us; speedup vs baseline: 1.9943x; 1.9943x over previous
//
#include <hip/hip_runtime.h>

// Problem constants (B=1)
#define CC   448   // channels
#define CGC  64    // key/query channels = C/K
#define MMM  7     // m groups (C = MMM*CGC)
#define HWSZ 4096  // H*W = 64*64
#define KK2  49    // K*K
#define GPH  32    // geometry-prior hidden

// Padded LDS tile: rows -3..66 -> 0..69, cols stored at c+4 (so 16B-aligned
// interior writes); read index = (row+di)*PCS + col+dj+1. Halo stays zero.
#define PR     70
#define PCS    72
#define PWORDS (PR*PCS)   // 5040

// Scrambled-unfold map (reference's unfold->(C,K2,L)->reshape(C,L,K2)):
// element (c, l', t) -> n = l'*49+t, tap p = n>>12, spatial l = n&4095.
__device__ __forceinline__ int win_off_global(int n, bool& ok) {
    int p  = n >> 12;
    int l  = n & 4095;
    int di = (p * 37) >> 8;    // p/7 exact for 0..48
    int dj = p - di * 7;
    int i  = (l >> 6) + di - 3;
    int j  = (l & 63) + dj - 3;
    ok = ((unsigned)i < 64u) & ((unsigned)j < 64u);
    return i * 64 + j;
}

// ---------------- Kernel 1: km/qm = conv1x1(x, Wk/Wq), 8 g per block -----
#define KQG 8
__global__ __launch_bounds__(128) void kq_kernel(
    const float* __restrict__ x,
    const float* __restrict__ Wk, const float* __restrict__ bk,
    const float* __restrict__ Wq, const float* __restrict__ bq,
    float* __restrict__ km, float* __restrict__ qm)
{
    __shared__ float wks[CC][KQG];
    __shared__ float wqs[CC][KQG];
    const int tid = threadIdx.x;
    const int g0  = blockIdx.y * KQG;
    const int l   = blockIdx.x * 128 + tid;
    for (int i = tid; i < CC * KQG; i += 128) {
        int gg = i & (KQG - 1), c = i >> 3;
        wks[c][gg] = Wk[(g0 + gg) * CC + c];
        wqs[c][gg] = Wq[(g0 + gg) * CC + c];
    }
    __syncthreads();
    float ak[KQG] = {0,0,0,0,0,0,0,0};
    float aq[KQG] = {0,0,0,0,0,0,0,0};
    #pragma unroll 2
    for (int c = 0; c < CC; ++c) {
        float xv = x[c * HWSZ + l];
        const float4* kp = (const float4*)&wks[c][0];
        const float4* qp = (const float4*)&wqs[c][0];
        float4 k0 = kp[0], k1 = kp[1];
        float4 q0 = qp[0], q1 = qp[1];
        ak[0] = fmaf(k0.x, xv, ak[0]); ak[1] = fmaf(k0.y, xv, ak[1]);
        ak[2] = fmaf(k0.z, xv, ak[2]); ak[3] = fmaf(k0.w, xv, ak[3]);
        ak[4] = fmaf(k1.x, xv, ak[4]); ak[5] = fmaf(k1.y, xv, ak[5]);
        ak[6] = fmaf(k1.z, xv, ak[6]); ak[7] = fmaf(k1.w, xv, ak[7]);
        aq[0] = fmaf(q0.x, xv, aq[0]); aq[1] = fmaf(q0.y, xv, aq[1]);
        aq[2] = fmaf(q0.z, xv, aq[2]); aq[3] = fmaf(q0.w, xv, aq[3]);
        aq[4] = fmaf(q1.x, xv, aq[4]); aq[5] = fmaf(q1.y, xv, aq[5]);
        aq[6] = fmaf(q1.z, xv, aq[6]); aq[7] = fmaf(q1.w, xv, aq[7]);
    }
    #pragma unroll
    for (int gg = 0; gg < KQG; ++gg) {
        km[(g0 + gg) * HWSZ + l] = ak[gg] + bk[g0 + gg];
        qm[(g0 + gg) * HWSZ + l] = aq[gg] + bq[g0 + gg];
    }
}

// ---------------- Kernel 2: geometry prior (64 x 49) ---------------------
__global__ __launch_bounds__(256) void gpk_kernel(
    const float* __restrict__ gw1, const float* __restrict__ gb1,
    const float* __restrict__ gw2, const float* __restrict__ gb2,
    float* __restrict__ gpk)
{
    const int idx = blockIdx.x * 256 + threadIdx.x;
    if (idx >= CGC * KK2) return;
    const int g = idx / KK2;
    const int t = idx - g * KK2;
    const int di = t / 7, dj = t - di * 7;
    const float xp = (float)(dj - 3);
    const float yp = (float)(3 - di);
    float acc = gb2[g];
    #pragma unroll
    for (int j = 0; j < GPH; ++j) {
        float h = gw1[j * 2 + 0] * xp + gw1[j * 2 + 1] * yp + gb1[j];
        h = fmaxf(h, 0.f);
        acc = fmaf(gw2[g * GPH + j], h, acc);
    }
    gpk[idx] = acc;
}

// ---------------- Kernel 3: attention + aggregation (LDS-staged) ---------
// Block: one g, 256 consecutive l'. km page + x pages staged into padded
// LDS tiles (zero halo == unfold zero-padding). Tap addrs computed once,
// reused across all 7 m pages.
__global__ __launch_bounds__(256) void attn_kernel(
    const float* __restrict__ km, const float* __restrict__ qm,
    const float* __restrict__ gpk, const float* __restrict__ x,
    float* __restrict__ pre)
{
    __shared__ float kpad[PWORDS];
    __shared__ float xpad[PWORDS];
    __shared__ float gpk_s[KK2];

    const int tid = threadIdx.x;
    const int g   = blockIdx.y;
    const int lp  = blockIdx.x * 256 + tid;
    const int n0  = lp * KK2;

    // zero both padded tiles (halo stays zero forever; interior overwritten)
    float4 z4 = {0.f, 0.f, 0.f, 0.f};
    for (int i = tid; i < PWORDS / 4; i += 256) {
        ((float4*)kpad)[i] = z4;
        ((float4*)xpad)[i] = z4;
    }
    __syncthreads();

    // stage km[g] page into kpad interior (16B-aligned b128 writes)
    const float* __restrict__ kmg = km + g * HWSZ;
    for (int i = tid; i < HWSZ / 4; i += 256) {
        float4 v = ((const float4*)kmg)[i];
        int w0 = i * 4;
        int r = w0 >> 6, c = w0 & 63;
        *((float4*)&kpad[(r + 3) * PCS + c + 4]) = v;
    }
    if (tid < KK2) gpk_s[tid] = gpk[g * KK2 + tid];

    // q center (one scattered global load per thread)
    float qc;
    {
        bool ok;
        int off = win_off_global(n0 + 24, ok);
        qc = ok ? qm[g * HWSZ + off] : 0.f;
    }
    __syncthreads();

    // Phase A: logits from kpad; remember tap addresses
    float a[KK2];
    int   adr[KK2];
    float mx = -1e30f;
    #pragma unroll
    for (int t = 0; t < KK2; ++t) {
        int n  = n0 + t;
        int p  = n >> 12;
        int l  = n & 4095;
        int di = (p * 37) >> 8;
        int dj = p - di * 7;
        int ad = ((l >> 6) + di) * PCS + (l & 63) + dj + 1;
        adr[t] = ad;
        float av = fmaf(kpad[ad], qc, gpk_s[t]);
        a[t] = av;
        mx = fmaxf(mx, av);
    }
    float d = 0.f;
    #pragma unroll
    for (int t = 0; t < KK2; ++t) {
        float e = __expf(a[t] - mx);
        a[t] = e;
        d += e;
    }
    const float inv = 1.f / d;
    #pragma unroll
    for (int t = 0; t < KK2; ++t) a[t] *= inv;

    // Phase B: per m, restage x page, accumulate with stored addrs
    for (int m = 0; m < MMM; ++m) {
        __syncthreads();   // previous readers of xpad done
        const float4* __restrict__ xg4 = (const float4*)(x + (m * CGC + g) * HWSZ);
        for (int i = tid; i < HWSZ / 4; i += 256) {
            float4 v = xg4[i];
            int w0 = i * 4;
            int r = w0 >> 6, c = w0 & 63;
            *((float4*)&xpad[(r + 3) * PCS + c + 4]) = v;
        }
        __syncthreads();
        float acc = 0.f;
        #pragma unroll
        for (int t = 0; t < KK2; ++t)
            acc = fmaf(a[t], xpad[adr[t]], acc);
        pre[(m * CGC + g) * HWSZ + lp] = acc;
    }
}

// ---------------- Kernel 4: final conv1x1 448 -> 448, 32 outs/block ------
#define FO 32
__global__ __launch_bounds__(256) void fconv_kernel(
    const float* __restrict__ pre,
    const float* __restrict__ Wf, const float* __restrict__ bfv,
    float* __restrict__ out)
{
    __shared__ float w_s[CC][FO];   // 57 KB, c-major
    const int tid = threadIdx.x;
    const int o0  = blockIdx.y * FO;
    const int l   = blockIdx.x * 256 + tid;
    for (int i = tid; i < CC * FO; i += 256) {
        int oo = i & (FO - 1), c = i >> 5;
        w_s[c][oo] = Wf[(o0 + oo) * CC + c];
    }
    __syncthreads();
    float acc[FO];
    #pragma unroll
    for (int oo = 0; oo < FO; ++oo) acc[oo] = 0.f;
    for (int c = 0; c < CC; ++c) {
        float pv = pre[c * HWSZ + l];
        const float4* wp = (const float4*)&w_s[c][0];
        #pragma unroll
        for (int ov = 0; ov < FO / 4; ++ov) {
            float4 w = wp[ov];
            acc[ov*4+0] = fmaf(w.x, pv, acc[ov*4+0]);
            acc[ov*4+1] = fmaf(w.y, pv, acc[ov*4+1]);
            acc[ov*4+2] = fmaf(w.z, pv, acc[ov*4+2]);
            acc[ov*4+3] = fmaf(w.w, pv, acc[ov*4+3]);
        }
    }
    #pragma unroll
    for (int oo = 0; oo < FO; ++oo)
        out[(o0 + oo) * HWSZ + l] = acc[oo] + bfv[o0 + oo];
}

extern "C" void kernel_launch(void* const* d_in, const int* in_sizes, int n_in,
                              void* d_out, int out_size, void* d_ws, size_t ws_size,
                              hipStream_t stream) {
    const float* x   = (const float*)d_in[0];
    const float* Wk  = (const float*)d_in[1];
    const float* bk  = (const float*)d_in[2];
    const float* Wq  = (const float*)d_in[3];
    const float* bq  = (const float*)d_in[4];
    const float* gw1 = (const float*)d_in[5];
    const float* gb1 = (const float*)d_in[6];
    const float* gw2 = (const float*)d_in[7];
    const float* gb2 = (const float*)d_in[8];
    const float* Wf  = (const float*)d_in[9];
    const float* bfv = (const float*)d_in[10];
    float* out = (float*)d_out;

    float* km  = (float*)d_ws;             // 64*4096
    float* qm  = km + CGC * HWSZ;          // 64*4096
    float* gpk = qm + CGC * HWSZ;          // 64*49
    float* pre = gpk + CGC * KK2;          // 448*4096

    kq_kernel  <<<dim3(32, CGC / KQG), 128, 0, stream>>>(x, Wk, bk, Wq, bq, km, qm);
    gpk_kernel <<<dim3(13),            256, 0, stream>>>(gw1, gb1, gw2, gb2, gpk);
    attn_kernel<<<dim3(16, CGC),       256, 0, stream>>>(km, qm, gpk, x, pre);
    fconv_kernel<<<dim3(16, CC / FO),  256, 0, stream>>>(pre, Wf, bfv, out);
}

// Round 4
// 149.402 us; speedup vs baseline: 3.4936x; 1.7518x over previous
//
#include <hip/hip_runtime.h>

// Problem constants (B=1)
#define CC   448   // channels
#define CGC  64    // key/query channels
#define MMM  7     // m groups
#define HWSZ 4096  // H*W
#define KK2  49    // K*K
#define GPH  32    // geometry-prior hidden

// attn linear-LDS page with zero guard bands.
// addr = GLO + l + (di-3)*64 + (dj-3): range [1, 4486] for l in [0,4096), di in [0,7), dj in [0,7).
#define GLO 196
#define GHI 260
#define XWORDS (GLO + HWSZ + GHI)   // 4552 words

__device__ __forceinline__ int win_off_global(int n, bool& ok) {
    int p  = n >> 12;
    int l  = n & 4095;
    int di = (p * 37) >> 8;    // p/7 exact for 0..48
    int dj = p - di * 7;
    int i  = (l >> 6) + di - 3;
    int j  = (l & 63) + dj - 3;
    ok = ((unsigned)i < 64u) && ((unsigned)j < 64u);
    return i * 64 + j;
}

// ------------- shared GEMM tile body: C[64, 4096-tile] = A[64,448] * B[448,4096] + bias -------------
// 256 threads; each computes 4x4. A row-major (64 rows at given base), B row-major, C row-major.
__device__ __forceinline__ void gemm_tile(
    const float* __restrict__ A, const float* __restrict__ B,
    const float* __restrict__ bias, float* __restrict__ C,
    int nT, int tid)
{
    __shared__ float As[32][68];   // [k][o], padded: 68 words = 272 B, 16B-multiple rows
    __shared__ float Bs[32][64];   // [k][l]
    const int tx = tid & 15, ty = tid >> 4;
    float acc[4][4];
    #pragma unroll
    for (int i = 0; i < 4; ++i)
        #pragma unroll
        for (int j = 0; j < 4; ++j) acc[i][j] = 0.f;

    for (int kT = 0; kT < CC; kT += 32) {
        #pragma unroll
        for (int it = 0; it < 2; ++it) {
            int e  = tid + it * 256;            // 0..511
            int r  = e >> 3, k4 = e & 7;        // A: 8 float4 per row, 64 rows
            float4 av = *(const float4*)(A + r * CC + kT + k4 * 4);
            As[k4*4+0][r] = av.x; As[k4*4+1][r] = av.y;
            As[k4*4+2][r] = av.z; As[k4*4+3][r] = av.w;
            int kr = e >> 4, l4 = e & 15;       // B: 16 float4 per row, 32 rows
            float4 bv = *(const float4*)(B + (size_t)(kT + kr) * HWSZ + nT + l4 * 4);
            *(float4*)&Bs[kr][l4 * 4] = bv;
        }
        __syncthreads();
        #pragma unroll
        for (int k = 0; k < 32; ++k) {
            float4 af = *(const float4*)&As[k][ty * 4];
            float4 bf = *(const float4*)&Bs[k][tx * 4];
            acc[0][0] = fmaf(af.x, bf.x, acc[0][0]); acc[0][1] = fmaf(af.x, bf.y, acc[0][1]);
            acc[0][2] = fmaf(af.x, bf.z, acc[0][2]); acc[0][3] = fmaf(af.x, bf.w, acc[0][3]);
            acc[1][0] = fmaf(af.y, bf.x, acc[1][0]); acc[1][1] = fmaf(af.y, bf.y, acc[1][1]);
            acc[1][2] = fmaf(af.y, bf.z, acc[1][2]); acc[1][3] = fmaf(af.y, bf.w, acc[1][3]);
            acc[2][0] = fmaf(af.z, bf.x, acc[2][0]); acc[2][1] = fmaf(af.z, bf.y, acc[2][1]);
            acc[2][2] = fmaf(af.z, bf.z, acc[2][2]); acc[2][3] = fmaf(af.z, bf.w, acc[2][3]);
            acc[3][0] = fmaf(af.w, bf.x, acc[3][0]); acc[3][1] = fmaf(af.w, bf.y, acc[3][1]);
            acc[3][2] = fmaf(af.w, bf.z, acc[3][2]); acc[3][3] = fmaf(af.w, bf.w, acc[3][3]);
        }
        __syncthreads();
    }
    #pragma unroll
    for (int i = 0; i < 4; ++i) {
        float bi = bias[ty * 4 + i];
        float4 o;
        o.x = acc[i][0] + bi; o.y = acc[i][1] + bi;
        o.z = acc[i][2] + bi; o.w = acc[i][3] + bi;
        *(float4*)(C + (size_t)(ty * 4 + i) * HWSZ + nT + tx * 4) = o;
    }
}

// ---------------- Kernel 1: km/qm via GEMM; blockIdx.y selects k vs q -----
__global__ __launch_bounds__(256) void kq_gemm(
    const float* __restrict__ x,
    const float* __restrict__ Wk, const float* __restrict__ bk,
    const float* __restrict__ Wq, const float* __restrict__ bq,
    float* __restrict__ km, float* __restrict__ qm)
{
    const bool isQ = (blockIdx.y != 0);
    const float* A    = isQ ? Wq : Wk;
    const float* bias = isQ ? bq : bk;
    float*       Cd   = isQ ? qm : km;
    gemm_tile(A, x, bias, Cd, blockIdx.x * 64, threadIdx.x);
}

// ---------------- Kernel 2: geometry prior (64 x 49) ---------------------
__global__ __launch_bounds__(256) void gpk_kernel(
    const float* __restrict__ gw1, const float* __restrict__ gb1,
    const float* __restrict__ gw2, const float* __restrict__ gb2,
    float* __restrict__ gpk)
{
    const int idx = blockIdx.x * 256 + threadIdx.x;
    if (idx >= CGC * KK2) return;
    const int g = idx / KK2;
    const int t = idx - g * KK2;
    const int di = t / 7, dj = t - di * 7;
    const float xp = (float)(dj - 3);
    const float yp = (float)(3 - di);
    float acc = gb2[g];
    #pragma unroll
    for (int j = 0; j < GPH; ++j) {
        float h = gw1[j * 2 + 0] * xp + gw1[j * 2 + 1] * yp + gb1[j];
        h = fmaxf(h, 0.f);
        acc = fmaf(gw2[g * GPH + j], h, acc);
    }
    gpk[idx] = acc;
}

// ---------------- Kernel 3: attention + aggregation ----------------------
// Block: one g, 512 consecutive l'. Linear LDS pages + zero guards.
// Per-thread taps n = lp*49+t are contiguous: <=2 segments with bases B0/B1;
// tap address = cndmask(B0,B1) + t (t folds into ds immediate). Row-OOB taps
// land in the zero guard automatically; only column-wrap needs a mask.
__global__ __launch_bounds__(512) void attn_kernel(
    const float* __restrict__ km, const float* __restrict__ qm,
    const float* __restrict__ gpk, const float* __restrict__ x,
    float* __restrict__ pre)
{
    __shared__ float klin[XWORDS];
    __shared__ float xlin[XWORDS];
    __shared__ float gpk_s[KK2];
    const int tid = threadIdx.x;
    const int g   = blockIdx.y;
    const int lp  = blockIdx.x * 512 + tid;

    // zero guard bands of both arrays: lo 49 float4, hi 65 float4 each
    if (tid < 114) {
        float4 z = {0.f, 0.f, 0.f, 0.f};
        int w = (tid < 49) ? tid * 4 : (GLO + HWSZ + (tid - 49) * 4);
        *(float4*)&klin[w] = z;
        *(float4*)&xlin[w] = z;
    }
    // stage km page (1024 float4 over 512 threads)
    {
        const float4* km4 = (const float4*)(km + (size_t)g * HWSZ);
        float4 va = km4[tid], vb = km4[tid + 512];
        *(float4*)&klin[GLO + tid * 4]         = va;
        *(float4*)&klin[GLO + (tid + 512) * 4] = vb;
    }
    if (tid < KK2) gpk_s[tid] = gpk[g * KK2 + tid];

    // q center (one scattered global load)
    float qc;
    { bool ok; int o = win_off_global(lp * KK2 + 24, ok); qc = ok ? qm[(size_t)g * HWSZ + o] : 0.f; }

    // per-thread segment constants
    const int n0 = lp * KK2;
    const int p0 = n0 >> 12;
    const int l0 = n0 & 4095;
    const int ts = ((p0 + 1) << 12) - n0;       // taps t<ts in segment 0
    const int di0 = (p0 * 37) >> 8, dj0 = p0 - di0 * 7;
    const int p1  = p0 + 1;
    const int di1 = (p1 * 37) >> 8, dj1 = p1 - di1 * 7;
    const int djm3_0 = dj0 - 3, djm3_1 = dj1 - 3;
    const int B0 = GLO + l0 + (di0 - 3) * 64 + djm3_0;
    const int B1 = GLO + l0 - 4096 + (di1 - 3) * 64 + djm3_1;
    __syncthreads();

    // Phase A: logits
    float a[KK2];
    float mx = -1e30f;
    #pragma unroll
    for (int t = 0; t < KK2; ++t) {
        bool s1 = (t >= ts);
        int base = s1 ? B1 : B0;
        float kv = klin[base + t];
        int jj = ((l0 + t) & 63) + (s1 ? djm3_1 : djm3_0);
        kv = ((unsigned)jj < 64u) ? kv : 0.f;
        float av = fmaf(kv, qc, gpk_s[t]);
        a[t] = av;
        mx = fmaxf(mx, av);
    }
    // softmax numerators (masked), full denominator
    float d = 0.f;
    #pragma unroll
    for (int t = 0; t < KK2; ++t) {
        float e = __expf(a[t] - mx);
        d += e;
        bool s1 = (t >= ts);
        int jj = ((l0 + t) & 63) + (s1 ? djm3_1 : djm3_0);
        a[t] = ((unsigned)jj < 64u) ? e : 0.f;
    }
    const float inv = 1.f / d;

    // Phase B: per m, restage x page, accumulate
    for (int m = 0; m < MMM; ++m) {
        const float4* xg4 = (const float4*)(x + (size_t)(m * CGC + g) * HWSZ);
        float4 va = xg4[tid], vb = xg4[tid + 512];
        __syncthreads();   // previous readers of xlin done
        *(float4*)&xlin[GLO + tid * 4]         = va;
        *(float4*)&xlin[GLO + (tid + 512) * 4] = vb;
        __syncthreads();
        float acc = 0.f;
        #pragma unroll
        for (int t = 0; t < KK2; ++t) {
            int base = (t >= ts) ? B1 : B0;
            acc = fmaf(a[t], xlin[base + t], acc);
        }
        pre[(size_t)(m * CGC + g) * HWSZ + lp] = acc * inv;
    }
}

// ---------------- Kernel 4: final conv via GEMM --------------------------
__global__ __launch_bounds__(256) void fconv_gemm(
    const float* __restrict__ pre,
    const float* __restrict__ Wf, const float* __restrict__ bfv,
    float* __restrict__ out)
{
    const int oT = blockIdx.y * 64;
    gemm_tile(Wf + (size_t)oT * CC, pre, bfv + oT, out + (size_t)oT * HWSZ,
              blockIdx.x * 64, threadIdx.x);
}

extern "C" void kernel_launch(void* const* d_in, const int* in_sizes, int n_in,
                              void* d_out, int out_size, void* d_ws, size_t ws_size,
                              hipStream_t stream) {
    const float* x   = (const float*)d_in[0];
    const float* Wk  = (const float*)d_in[1];
    const float* bk  = (const float*)d_in[2];
    const float* Wq  = (const float*)d_in[3];
    const float* bq  = (const float*)d_in[4];
    const float* gw1 = (const float*)d_in[5];
    const float* gb1 = (const float*)d_in[6];
    const float* gw2 = (const float*)d_in[7];
    const float* gb2 = (const float*)d_in[8];
    const float* Wf  = (const float*)d_in[9];
    const float* bfv = (const float*)d_in[10];
    float* out = (float*)d_out;

    float* km  = (float*)d_ws;             // 64*4096
    float* qm  = km + CGC * HWSZ;          // 64*4096
    float* gpk = qm + CGC * HWSZ;          // 64*49
    float* pre = gpk + CGC * KK2;          // 448*4096

    kq_gemm   <<<dim3(64, 2),  256, 0, stream>>>(x, Wk, bk, Wq, bq, km, qm);
    gpk_kernel<<<dim3(13),     256, 0, stream>>>(gw1, gb1, gw2, gb2, gpk);
    attn_kernel<<<dim3(8, CGC), 512, 0, stream>>>(km, qm, gpk, x, pre);
    fconv_gemm<<<dim3(64, 7),  256, 0, stream>>>(pre, Wf, bfv, out);
}

// Round 5
// 133.286 us; speedup vs baseline: 3.9160x; 1.1209x over previous
//
#include <hip/hip_runtime.h>
#include <hip/hip_bf16.h>

// Problem constants (B=1)
#define CC   448   // channels
#define CGC  64    // key/query channels
#define MMM  7     // m groups
#define HWSZ 4096  // H*W
#define KK2  49    // K*K
#define GPH  32    // geometry-prior hidden

typedef __attribute__((ext_vector_type(8))) short   short8;   // 8 bf16 (4 VGPRs)
typedef __attribute__((ext_vector_type(4))) float   f32x4;
typedef __attribute__((ext_vector_type(4))) unsigned short us4;

__device__ __forceinline__ unsigned short f2b(float f) {
    union { __hip_bfloat16 h; unsigned short u; } cv;
    cv.h = __float2bfloat16(f);
    return cv.u;
}

// ---------------- MFMA GEMM strip: C[64 x 4096-tile] = A[64,448]*B[448,4096] + bias ----
// 256 threads = 4 waves (2x2 of 32x32). LDS frag layout [kg][m|n][j] -> each frag read is
// one conflict-free ds_read_b128 (quarter-waves sweep 256B = all 32 banks).
__device__ __forceinline__ void mfma_gemm64(
    const float* __restrict__ A,    // 64 x 448 strip, row-major (lda=448)
    const float* __restrict__ B,    // 448 x 4096, row-major
    const float* __restrict__ bias, // 64
    float* __restrict__ C,          // strip base, row-major (ldc=4096)
    int nT, int tid)
{
    __shared__ unsigned short As[2048];   // 4 KB  [kg(4)][m(64)][j(8)]
    __shared__ unsigned short Bs[2048];   // 4 KB  [kg(4)][n(64)][j(8)]
    __shared__ float bias_s[64];
    if (tid < 64) bias_s[tid] = bias[tid];

    const int lane = tid & 63;
    const int wid  = tid >> 6;
    const int wm   = (wid >> 1) * 32;
    const int wn   = (wid & 1) * 32;
    const int l15  = lane & 15;
    const int l4   = lane >> 4;

    f32x4 acc[2][2];
    #pragma unroll
    for (int i = 0; i < 2; ++i)
        #pragma unroll
        for (int j = 0; j < 2; ++j)
            acc[i][j] = (f32x4){0.f, 0.f, 0.f, 0.f};

    for (int kt = 0; kt < 14; ++kt) {
        // stage A: 64 rows x 32 k (fp32 -> bf16), layout [kg][m][j]
        #pragma unroll
        for (int it = 0; it < 2; ++it) {
            int ee = tid + it * 256;          // 0..511
            int m = ee >> 3, k4 = ee & 7;     // k4: which float4 of the 32-k chunk
            float4 v = *(const float4*)(A + m * CC + kt * 32 + k4 * 4);
            us4 w = { f2b(v.x), f2b(v.y), f2b(v.z), f2b(v.w) };
            *(us4*)&As[(k4 >> 1) * 512 + m * 8 + (k4 & 1) * 4] = w;
        }
        // stage B with transpose: 32 k-rows x 64 n, layout [kg][n][j]
        #pragma unroll
        for (int it = 0; it < 2; ++it) {
            int ee = tid + it * 256;
            int k = ee >> 4, n4 = ee & 15;
            float4 v = *(const float4*)(B + (size_t)(kt * 32 + k) * HWSZ + nT + n4 * 4);
            int base = (k >> 3) * 512 + n4 * 32 + (k & 7);
            Bs[base]      = f2b(v.x);
            Bs[base + 8]  = f2b(v.y);
            Bs[base + 16] = f2b(v.z);
            Bs[base + 24] = f2b(v.w);
        }
        __syncthreads();
        short8 a0 = *(short8*)&As[l4 * 512 + (wm + l15) * 8];
        short8 a1 = *(short8*)&As[l4 * 512 + (wm + 16 + l15) * 8];
        short8 b0 = *(short8*)&Bs[l4 * 512 + (wn + l15) * 8];
        short8 b1 = *(short8*)&Bs[l4 * 512 + (wn + 16 + l15) * 8];
        acc[0][0] = __builtin_amdgcn_mfma_f32_16x16x32_bf16(a0, b0, acc[0][0], 0, 0, 0);
        acc[0][1] = __builtin_amdgcn_mfma_f32_16x16x32_bf16(a0, b1, acc[0][1], 0, 0, 0);
        acc[1][0] = __builtin_amdgcn_mfma_f32_16x16x32_bf16(a1, b0, acc[1][0], 0, 0, 0);
        acc[1][1] = __builtin_amdgcn_mfma_f32_16x16x32_bf16(a1, b1, acc[1][1], 0, 0, 0);
        __syncthreads();
    }
    // epilogue: C/D layout col=lane&15, row=(lane>>4)*4+reg  [verified m89]
    #pragma unroll
    for (int wm2 = 0; wm2 < 2; ++wm2)
        #pragma unroll
        for (int wn2 = 0; wn2 < 2; ++wn2)
            #pragma unroll
            for (int r = 0; r < 4; ++r) {
                int row = wm + wm2 * 16 + l4 * 4 + r;
                int col = wn + wn2 * 16 + l15;
                C[(size_t)row * HWSZ + nT + col] = acc[wm2][wn2][r] + bias_s[row];
            }
}

// ---------------- Kernel 1: km/qm via MFMA GEMM --------------------------
__global__ __launch_bounds__(256) void kq_mfma(
    const float* __restrict__ x,
    const float* __restrict__ Wk, const float* __restrict__ bk,
    const float* __restrict__ Wq, const float* __restrict__ bq,
    float* __restrict__ km, float* __restrict__ qm)
{
    const bool isQ = (blockIdx.y != 0);
    mfma_gemm64(isQ ? Wq : Wk, x, isQ ? bq : bk, isQ ? qm : km,
                blockIdx.x * 64, threadIdx.x);
}

// ---------------- Kernel 3 epilogue conv: out = Wf*pre + bf ---------------
__global__ __launch_bounds__(256) void fconv_mfma(
    const float* __restrict__ pre,
    const float* __restrict__ Wf, const float* __restrict__ bfv,
    float* __restrict__ out)
{
    const int mt = blockIdx.y;
    mfma_gemm64(Wf + (size_t)mt * 64 * CC, pre, bfv + mt * 64,
                out + (size_t)mt * 64 * HWSZ, blockIdx.x * 64, threadIdx.x);
}

// ---------------- Kernel 2: attention + aggregation (gpk fused) ----------
#define GLO 196
#define GHI 260
#define XWORDS (GLO + HWSZ + GHI)   // 4552 words

__device__ __forceinline__ int win_off_global(int n, bool& ok) {
    int p  = n >> 12;
    int l  = n & 4095;
    int di = (p * 37) >> 8;    // p/7 exact for 0..48
    int dj = p - di * 7;
    int i  = (l >> 6) + di - 3;
    int j  = (l & 63) + dj - 3;
    ok = ((unsigned)i < 64u) && ((unsigned)j < 64u);
    return i * 64 + j;
}

__global__ __launch_bounds__(512) void attn_kernel(
    const float* __restrict__ km, const float* __restrict__ qm,
    const float* __restrict__ x,
    const float* __restrict__ gw1, const float* __restrict__ gb1,
    const float* __restrict__ gw2, const float* __restrict__ gb2,
    float* __restrict__ pre)
{
    __shared__ float klin[XWORDS];
    __shared__ float xlin[XWORDS];
    __shared__ float gpk_s[KK2];
    const int tid = threadIdx.x;
    const int g   = blockIdx.y;
    const int lp  = blockIdx.x * 512 + tid;

    // zero guard bands: lo 49 float4, hi 65 float4 each
    if (tid < 114) {
        float4 z = {0.f, 0.f, 0.f, 0.f};
        int w = (tid < 49) ? tid * 4 : (GLO + HWSZ + (tid - 49) * 4);
        *(float4*)&klin[w] = z;
        *(float4*)&xlin[w] = z;
    }
    // stage km page
    {
        const float4* km4 = (const float4*)(km + (size_t)g * HWSZ);
        float4 va = km4[tid], vb = km4[tid + 512];
        *(float4*)&klin[GLO + tid * 4]         = va;
        *(float4*)&klin[GLO + (tid + 512) * 4] = vb;
    }
    // fused geometry prior: row g of gpk (49 values)
    if (tid < KK2) {
        int di = tid / 7, dj = tid - di * 7;
        float xp = (float)(dj - 3);
        float yp = (float)(3 - di);
        float acc = gb2[g];
        #pragma unroll
        for (int j = 0; j < GPH; ++j) {
            float h = gw1[j * 2 + 0] * xp + gw1[j * 2 + 1] * yp + gb1[j];
            h = fmaxf(h, 0.f);
            acc = fmaf(gw2[g * GPH + j], h, acc);
        }
        gpk_s[tid] = acc;
    }

    // q center
    float qc;
    { bool ok; int o = win_off_global(lp * KK2 + 24, ok); qc = ok ? qm[(size_t)g * HWSZ + o] : 0.f; }

    // per-thread segment constants (taps contiguous in <=2 segments)
    const int n0 = lp * KK2;
    const int p0 = n0 >> 12;
    const int l0 = n0 & 4095;
    const int ts = ((p0 + 1) << 12) - n0;
    const int di0 = (p0 * 37) >> 8, dj0 = p0 - di0 * 7;
    const int p1  = p0 + 1;
    const int di1 = (p1 * 37) >> 8, dj1 = p1 - di1 * 7;
    const int djm3_0 = dj0 - 3, djm3_1 = dj1 - 3;
    const int B0 = GLO + l0 + (di0 - 3) * 64 + djm3_0;
    const int B1 = GLO + l0 - 4096 + (di1 - 3) * 64 + djm3_1;
    __syncthreads();

    // Phase A: logits
    float a[KK2];
    float mx = -1e30f;
    #pragma unroll
    for (int t = 0; t < KK2; ++t) {
        bool s1 = (t >= ts);
        int base = s1 ? B1 : B0;
        float kv = klin[base + t];
        int jj = ((l0 + t) & 63) + (s1 ? djm3_1 : djm3_0);
        kv = ((unsigned)jj < 64u) ? kv : 0.f;
        float av = fmaf(kv, qc, gpk_s[t]);
        a[t] = av;
        mx = fmaxf(mx, av);
    }
    float d = 0.f;
    #pragma unroll
    for (int t = 0; t < KK2; ++t) {
        float e = __expf(a[t] - mx);
        d += e;                                  // padded taps count in denominator
        bool s1 = (t >= ts);
        int jj = ((l0 + t) & 63) + (s1 ? djm3_1 : djm3_0);
        a[t] = ((unsigned)jj < 64u) ? e : 0.f;
    }
    const float inv = 1.f / d;

    // Phase B: per m, restage x page, accumulate
    for (int m = 0; m < MMM; ++m) {
        const float4* xg4 = (const float4*)(x + (size_t)(m * CGC + g) * HWSZ);
        float4 va = xg4[tid], vb = xg4[tid + 512];
        __syncthreads();
        *(float4*)&xlin[GLO + tid * 4]         = va;
        *(float4*)&xlin[GLO + (tid + 512) * 4] = vb;
        __syncthreads();
        float acc = 0.f;
        #pragma unroll
        for (int t = 0; t < KK2; ++t) {
            int base = (t >= ts) ? B1 : B0;
            acc = fmaf(a[t], xlin[base + t], acc);
        }
        pre[(size_t)(m * CGC + g) * HWSZ + lp] = acc * inv;
    }
}

extern "C" void kernel_launch(void* const* d_in, const int* in_sizes, int n_in,
                              void* d_out, int out_size, void* d_ws, size_t ws_size,
                              hipStream_t stream) {
    const float* x   = (const float*)d_in[0];
    const float* Wk  = (const float*)d_in[1];
    const float* bk  = (const float*)d_in[2];
    const float* Wq  = (const float*)d_in[3];
    const float* bq  = (const float*)d_in[4];
    const float* gw1 = (const float*)d_in[5];
    const float* gb1 = (const float*)d_in[6];
    const float* gw2 = (const float*)d_in[7];
    const float* gb2 = (const float*)d_in[8];
    const float* Wf  = (const float*)d_in[9];
    const float* bfv = (const float*)d_in[10];
    float* out = (float*)d_out;

    float* km  = (float*)d_ws;             // 64*4096
    float* qm  = km + CGC * HWSZ;          // 64*4096
    float* pre = qm + CGC * HWSZ;          // 448*4096

    kq_mfma   <<<dim3(64, 2),   256, 0, stream>>>(x, Wk, bk, Wq, bq, km, qm);
    attn_kernel<<<dim3(8, CGC), 512, 0, stream>>>(km, qm, x, gw1, gb1, gw2, gb2, pre);
    fconv_mfma<<<dim3(64, 7),   256, 0, stream>>>(pre, Wf, bfv, out);
}

// Round 6
// 118.846 us; speedup vs baseline: 4.3918x; 1.1215x over previous
//
#include <hip/hip_runtime.h>
#include <hip/hip_bf16.h>

// Problem constants (B=1)
#define CC   448   // channels
#define CGC  64    // key/query channels
#define MMM  7     // m groups
#define HWSZ 4096  // H*W
#define KK2  49    // K*K
#define GPH  32    // geometry-prior hidden

typedef __attribute__((ext_vector_type(8))) short   short8;   // 8 bf16 (4 VGPRs)
typedef __attribute__((ext_vector_type(4))) float   f32x4;
typedef __attribute__((ext_vector_type(4))) unsigned short us4;

__device__ __forceinline__ unsigned short f2b(float f) {
    union { __hip_bfloat16 h; unsigned short u; } cv;
    cv.h = __float2bfloat16(f);
    return cv.u;
}

// ---------------- MFMA GEMM strip: C[64 x 4096-tile] = A[64,448]*B[448,4096] + bias ----
// 256 threads = 4 waves (2x2 of 32x32). LDS frag layout [kg][m|n][j]: each frag read is
// one conflict-free ds_read_b128. Register-prefetch double buffering: kt+1 global loads
// issue before kt's first barrier, overlapping MFMA + both barriers.
__device__ __forceinline__ void mfma_gemm64(
    const float* __restrict__ A,    // 64 x 448 strip, row-major (lda=448)
    const float* __restrict__ B,    // 448 x 4096, row-major
    const float* __restrict__ bias, // 64
    float* __restrict__ C,          // strip base, row-major (ldc=4096)
    int nT, int tid)
{
    __shared__ unsigned short As[2048];   // 4 KB  [kg(4)][m(64)][j(8)]
    __shared__ unsigned short Bs[2048];   // 4 KB  [kg(4)][n(64)][j(8)]
    __shared__ float bias_s[64];
    if (tid < 64) bias_s[tid] = bias[tid];

    const int lane = tid & 63;
    const int wid  = tid >> 6;
    const int wm   = (wid >> 1) * 32;
    const int wn   = (wid & 1) * 32;
    const int l15  = lane & 15;
    const int l4   = lane >> 4;

    // loop-invariant staging indices (it = 0,1 -> e = tid, tid+256)
    const int am0 = tid >> 3,          ak0 = tid & 7;
    const int am1 = (tid + 256) >> 3,  ak1 = (tid + 256) & 7;
    const int bk0 = tid >> 4,          bn0 = tid & 15;
    const int bk1 = (tid + 256) >> 4,  bn1 = (tid + 256) & 15;

    f32x4 acc[2][2];
    #pragma unroll
    for (int i = 0; i < 2; ++i)
        #pragma unroll
        for (int j = 0; j < 2; ++j)
            acc[i][j] = (f32x4){0.f, 0.f, 0.f, 0.f};

    // prologue: load kt=0 tiles into registers
    float4 a0 = *(const float4*)(A + am0 * CC + ak0 * 4);
    float4 a1 = *(const float4*)(A + am1 * CC + ak1 * 4);
    float4 b0 = *(const float4*)(B + (size_t)bk0 * HWSZ + nT + bn0 * 4);
    float4 b1 = *(const float4*)(B + (size_t)bk1 * HWSZ + nT + bn1 * 4);

    for (int kt = 0; kt < 14; ++kt) {
        // write current tiles to LDS (fp32 -> bf16)
        {
            us4 w0 = { f2b(a0.x), f2b(a0.y), f2b(a0.z), f2b(a0.w) };
            *(us4*)&As[(ak0 >> 1) * 512 + am0 * 8 + (ak0 & 1) * 4] = w0;
            us4 w1 = { f2b(a1.x), f2b(a1.y), f2b(a1.z), f2b(a1.w) };
            *(us4*)&As[(ak1 >> 1) * 512 + am1 * 8 + (ak1 & 1) * 4] = w1;
            int base0 = (bk0 >> 3) * 512 + bn0 * 32 + (bk0 & 7);
            Bs[base0]      = f2b(b0.x);
            Bs[base0 + 8]  = f2b(b0.y);
            Bs[base0 + 16] = f2b(b0.z);
            Bs[base0 + 24] = f2b(b0.w);
            int base1 = (bk1 >> 3) * 512 + bn1 * 32 + (bk1 & 7);
            Bs[base1]      = f2b(b1.x);
            Bs[base1 + 8]  = f2b(b1.y);
            Bs[base1 + 16] = f2b(b1.z);
            Bs[base1 + 24] = f2b(b1.w);
        }
        // prefetch next tiles (overlaps barriers + MFMA below)
        if (kt < 13) {
            int ko = (kt + 1) * 32;
            a0 = *(const float4*)(A + am0 * CC + ko + ak0 * 4);
            a1 = *(const float4*)(A + am1 * CC + ko + ak1 * 4);
            b0 = *(const float4*)(B + (size_t)(ko + bk0) * HWSZ + nT + bn0 * 4);
            b1 = *(const float4*)(B + (size_t)(ko + bk1) * HWSZ + nT + bn1 * 4);
        }
        __syncthreads();
        short8 fa0 = *(short8*)&As[l4 * 512 + (wm + l15) * 8];
        short8 fa1 = *(short8*)&As[l4 * 512 + (wm + 16 + l15) * 8];
        short8 fb0 = *(short8*)&Bs[l4 * 512 + (wn + l15) * 8];
        short8 fb1 = *(short8*)&Bs[l4 * 512 + (wn + 16 + l15) * 8];
        acc[0][0] = __builtin_amdgcn_mfma_f32_16x16x32_bf16(fa0, fb0, acc[0][0], 0, 0, 0);
        acc[0][1] = __builtin_amdgcn_mfma_f32_16x16x32_bf16(fa0, fb1, acc[0][1], 0, 0, 0);
        acc[1][0] = __builtin_amdgcn_mfma_f32_16x16x32_bf16(fa1, fb0, acc[1][0], 0, 0, 0);
        acc[1][1] = __builtin_amdgcn_mfma_f32_16x16x32_bf16(fa1, fb1, acc[1][1], 0, 0, 0);
        __syncthreads();
    }
    // epilogue: C/D layout col=lane&15, row=(lane>>4)*4+reg  [verified m89]
    #pragma unroll
    for (int wm2 = 0; wm2 < 2; ++wm2)
        #pragma unroll
        for (int wn2 = 0; wn2 < 2; ++wn2)
            #pragma unroll
            for (int r = 0; r < 4; ++r) {
                int row = wm + wm2 * 16 + l4 * 4 + r;
                int col = wn + wn2 * 16 + l15;
                C[(size_t)row * HWSZ + nT + col] = acc[wm2][wn2][r] + bias_s[row];
            }
}

// ---------------- Kernel 1: km/qm via MFMA GEMM --------------------------
__global__ __launch_bounds__(256) void kq_mfma(
    const float* __restrict__ x,
    const float* __restrict__ Wk, const float* __restrict__ bk,
    const float* __restrict__ Wq, const float* __restrict__ bq,
    float* __restrict__ km, float* __restrict__ qm)
{
    const bool isQ = (blockIdx.y != 0);
    mfma_gemm64(isQ ? Wq : Wk, x, isQ ? bq : bk, isQ ? qm : km,
                blockIdx.x * 64, threadIdx.x);
}

// ---------------- Kernel 3: out = Wf*pre + bf ----------------------------
__global__ __launch_bounds__(256) void fconv_mfma(
    const float* __restrict__ pre,
    const float* __restrict__ Wf, const float* __restrict__ bfv,
    float* __restrict__ out)
{
    const int mt = blockIdx.y;
    mfma_gemm64(Wf + (size_t)mt * 64 * CC, pre, bfv + mt * 64,
                out + (size_t)mt * 64 * HWSZ, blockIdx.x * 64, threadIdx.x);
}

// ---------------- Kernel 2: attention + aggregation (gpk fused) ----------
#define GLO 196
#define GHI 260
#define XWORDS (GLO + HWSZ + GHI)   // 4552 words

__device__ __forceinline__ int win_off_global(int n, bool& ok) {
    int p  = n >> 12;
    int l  = n & 4095;
    int di = (p * 37) >> 8;    // p/7 exact for 0..48
    int dj = p - di * 7;
    int i  = (l >> 6) + di - 3;
    int j  = (l & 63) + dj - 3;
    ok = ((unsigned)i < 64u) && ((unsigned)j < 64u);
    return i * 64 + j;
}

// 256 threads, grid (16, 64): 4 blocks/CU. x-page staging software-pipelined
// through registers (xr -> LDS while next page loads into xn).
__global__ __launch_bounds__(256) void attn_kernel(
    const float* __restrict__ km, const float* __restrict__ qm,
    const float* __restrict__ x,
    const float* __restrict__ gw1, const float* __restrict__ gb1,
    const float* __restrict__ gw2, const float* __restrict__ gb2,
    float* __restrict__ pre)
{
    __shared__ float klin[XWORDS];
    __shared__ float xlin[XWORDS];
    __shared__ float gpk_s[KK2];
    const int tid = threadIdx.x;
    const int g   = blockIdx.y;
    const int lp  = blockIdx.x * 256 + tid;

    // zero guard bands: lo 49 float4, hi 65 float4 each
    if (tid < 114) {
        float4 z = {0.f, 0.f, 0.f, 0.f};
        int w = (tid < 49) ? tid * 4 : (GLO + HWSZ + (tid - 49) * 4);
        *(float4*)&klin[w] = z;
        *(float4*)&xlin[w] = z;
    }
    // stage km page: 256 threads x 4 float4
    {
        const float4* km4 = (const float4*)(km + (size_t)g * HWSZ);
        #pragma unroll
        for (int i = 0; i < 4; ++i) {
            int idx = tid + i * 256;
            *(float4*)&klin[GLO + idx * 4] = km4[idx];
        }
    }
    // fused geometry prior: row g (49 values)
    if (tid < KK2) {
        int di = tid / 7, dj = tid - di * 7;
        float xp = (float)(dj - 3);
        float yp = (float)(3 - di);
        float acc = gb2[g];
        #pragma unroll
        for (int j = 0; j < GPH; ++j) {
            float h = gw1[j * 2 + 0] * xp + gw1[j * 2 + 1] * yp + gb1[j];
            h = fmaxf(h, 0.f);
            acc = fmaf(gw2[g * GPH + j], h, acc);
        }
        gpk_s[tid] = acc;
    }

    // q center
    float qc;
    { bool ok; int o = win_off_global(lp * KK2 + 24, ok); qc = ok ? qm[(size_t)g * HWSZ + o] : 0.f; }

    // per-thread segment constants (taps contiguous in <=2 segments)
    const int n0 = lp * KK2;
    const int p0 = n0 >> 12;
    const int l0 = n0 & 4095;
    const int ts = ((p0 + 1) << 12) - n0;
    const int di0 = (p0 * 37) >> 8, dj0 = p0 - di0 * 7;
    const int p1  = p0 + 1;
    const int di1 = (p1 * 37) >> 8, dj1 = p1 - di1 * 7;
    const int djm3_0 = dj0 - 3, djm3_1 = dj1 - 3;
    const int B0 = GLO + l0 + (di0 - 3) * 64 + djm3_0;
    const int B1 = GLO + l0 - 4096 + (di1 - 3) * 64 + djm3_1;

    // prologue: m=0 x page into registers (overlaps phase A)
    float4 xr0, xr1, xr2, xr3;
    {
        const float4* xg4 = (const float4*)(x + (size_t)g * HWSZ);
        xr0 = xg4[tid]; xr1 = xg4[tid + 256]; xr2 = xg4[tid + 512]; xr3 = xg4[tid + 768];
    }
    __syncthreads();   // klin/guards/gpk staged

    // Phase A: logits
    float a[KK2];
    float mx = -1e30f;
    #pragma unroll
    for (int t = 0; t < KK2; ++t) {
        bool s1 = (t >= ts);
        int base = s1 ? B1 : B0;
        float kv = klin[base + t];
        int jj = ((l0 + t) & 63) + (s1 ? djm3_1 : djm3_0);
        kv = ((unsigned)jj < 64u) ? kv : 0.f;
        float av = fmaf(kv, qc, gpk_s[t]);
        a[t] = av;
        mx = fmaxf(mx, av);
    }
    float d = 0.f;
    #pragma unroll
    for (int t = 0; t < KK2; ++t) {
        float e = __expf(a[t] - mx);
        d += e;                                  // padded taps count in denominator
        bool s1 = (t >= ts);
        int jj = ((l0 + t) & 63) + (s1 ? djm3_1 : djm3_0);
        a[t] = ((unsigned)jj < 64u) ? e : 0.f;
    }
    const float inv = 1.f / d;

    // Phase B: per m, write staged page, prefetch next, accumulate
    #pragma unroll 1
    for (int m = 0; m < MMM; ++m) {
        __syncthreads();   // prior readers of xlin done
        *(float4*)&xlin[GLO + tid * 4]          = xr0;
        *(float4*)&xlin[GLO + (tid + 256) * 4]  = xr1;
        *(float4*)&xlin[GLO + (tid + 512) * 4]  = xr2;
        *(float4*)&xlin[GLO + (tid + 768) * 4]  = xr3;
        if (m < MMM - 1) {
            const float4* xg4 = (const float4*)(x + (size_t)((m + 1) * CGC + g) * HWSZ);
            xr0 = xg4[tid]; xr1 = xg4[tid + 256]; xr2 = xg4[tid + 512]; xr3 = xg4[tid + 768];
        }
        __syncthreads();
        float acc = 0.f;
        #pragma unroll
        for (int t = 0; t < KK2; ++t) {
            int base = (t >= ts) ? B1 : B0;
            acc = fmaf(a[t], xlin[base + t], acc);
        }
        pre[(size_t)(m * CGC + g) * HWSZ + lp] = acc * inv;
    }
}

extern "C" void kernel_launch(void* const* d_in, const int* in_sizes, int n_in,
                              void* d_out, int out_size, void* d_ws, size_t ws_size,
                              hipStream_t stream) {
    const float* x   = (const float*)d_in[0];
    const float* Wk  = (const float*)d_in[1];
    const float* bk  = (const float*)d_in[2];
    const float* Wq  = (const float*)d_in[3];
    const float* bq  = (const float*)d_in[4];
    const float* gw1 = (const float*)d_in[5];
    const float* gb1 = (const float*)d_in[6];
    const float* gw2 = (const float*)d_in[7];
    const float* gb2 = (const float*)d_in[8];
    const float* Wf  = (const float*)d_in[9];
    const float* bfv = (const float*)d_in[10];
    float* out = (float*)d_out;

    float* km  = (float*)d_ws;             // 64*4096
    float* qm  = km + CGC * HWSZ;          // 64*4096
    float* pre = qm + CGC * HWSZ;          // 448*4096

    kq_mfma    <<<dim3(64, 2),  256, 0, stream>>>(x, Wk, bk, Wq, bq, km, qm);
    attn_kernel<<<dim3(16, CGC), 256, 0, stream>>>(km, qm, x, gw1, gb1, gw2, gb2, pre);
    fconv_mfma <<<dim3(64, 7),  256, 0, stream>>>(pre, Wf, bfv, out);
}

// Round 7
// 115.875 us; speedup vs baseline: 4.5044x; 1.0256x over previous
//
#include <hip/hip_runtime.h>
#include <hip/hip_bf16.h>

// Problem constants (B=1)
#define CC   448   // channels
#define CGC  64    // key/query channels
#define MMM  7     // m groups
#define HWSZ 4096  // H*W
#define KK2  49    // K*K
#define GPH  32    // geometry-prior hidden

typedef __attribute__((ext_vector_type(8))) short   short8;   // 8 bf16 (4 VGPRs)
typedef __attribute__((ext_vector_type(4))) float   f32x4;
typedef __attribute__((ext_vector_type(4))) unsigned short us4;

__device__ __forceinline__ unsigned short f2b(float f) {
    union { __hip_bfloat16 h; unsigned short u; } cv;
    cv.h = __float2bfloat16(f);
    return cv.u;
}

// ---------------- Kernel 1: fused k+q GEMM ------------------------------
// C[128, 4096] = [Wk;Wq](128x448) @ x(448x4096). Tile 128x32, 256 thr = 4 waves,
// each wave 32 rows x 32 cols (2x2 MFMA 16x16x32). Grid 128 blocks.
// Staging reps are row-uniform: reps 0-1 stage Wk rows, reps 2-3 stage Wq rows.
// Epilogue wave-uniform: waves 0-1 -> km, waves 2-3 -> qm.
__global__ __launch_bounds__(256) void kq_mfma(
    const float* __restrict__ x,
    const float* __restrict__ Wk, const float* __restrict__ bk,
    const float* __restrict__ Wq, const float* __restrict__ bq,
    float* __restrict__ km, float* __restrict__ qm)
{
    __shared__ unsigned short As[4096];   // 8 KB  [kg(4)][m(128)][j(8)]
    __shared__ unsigned short Bs[1024];   // 2 KB  [kg(4)][n(32)][j(8)]

    const int tid  = threadIdx.x;
    const int nT   = blockIdx.x * 32;
    const int lane = tid & 63;
    const int wid  = tid >> 6;
    const int wm   = wid * 32;
    const int l15  = lane & 15;
    const int l4   = lane >> 4;

    const int ar = tid >> 3;          // 0..31: A row within rep
    const int ak = tid & 7;           // which float4 of the 32-k chunk
    const int bkr = tid >> 3;         // 0..31: B k-row
    const int bn4 = tid & 7;          // 0..7: B float4 col group

    f32x4 acc[2][2];
    #pragma unroll
    for (int i = 0; i < 2; ++i)
        #pragma unroll
        for (int j = 0; j < 2; ++j)
            acc[i][j] = (f32x4){0.f, 0.f, 0.f, 0.f};

    // prologue loads (kt = 0)
    float4 a0 = *(const float4*)(Wk + (size_t)ar * CC + ak * 4);
    float4 a1 = *(const float4*)(Wk + (size_t)(ar + 32) * CC + ak * 4);
    float4 a2 = *(const float4*)(Wq + (size_t)ar * CC + ak * 4);
    float4 a3 = *(const float4*)(Wq + (size_t)(ar + 32) * CC + ak * 4);
    float4 b0 = *(const float4*)(x + (size_t)bkr * HWSZ + nT + bn4 * 4);

    for (int kt = 0; kt < 14; ++kt) {
        // write LDS (fp32 -> bf16)
        {
            int kg = ak >> 1, jo = (ak & 1) * 4;
            us4 w;
            w = (us4){ f2b(a0.x), f2b(a0.y), f2b(a0.z), f2b(a0.w) };
            *(us4*)&As[kg * 1024 + (ar +  0) * 8 + jo] = w;
            w = (us4){ f2b(a1.x), f2b(a1.y), f2b(a1.z), f2b(a1.w) };
            *(us4*)&As[kg * 1024 + (ar + 32) * 8 + jo] = w;
            w = (us4){ f2b(a2.x), f2b(a2.y), f2b(a2.z), f2b(a2.w) };
            *(us4*)&As[kg * 1024 + (ar + 64) * 8 + jo] = w;
            w = (us4){ f2b(a3.x), f2b(a3.y), f2b(a3.z), f2b(a3.w) };
            *(us4*)&As[kg * 1024 + (ar + 96) * 8 + jo] = w;
            int base = (bkr >> 3) * 256 + bn4 * 32 + (bkr & 7);
            Bs[base]      = f2b(b0.x);
            Bs[base + 8]  = f2b(b0.y);
            Bs[base + 16] = f2b(b0.z);
            Bs[base + 24] = f2b(b0.w);
        }
        if (kt < 13) {
            int ko = (kt + 1) * 32;
            a0 = *(const float4*)(Wk + (size_t)ar * CC + ko + ak * 4);
            a1 = *(const float4*)(Wk + (size_t)(ar + 32) * CC + ko + ak * 4);
            a2 = *(const float4*)(Wq + (size_t)ar * CC + ko + ak * 4);
            a3 = *(const float4*)(Wq + (size_t)(ar + 32) * CC + ko + ak * 4);
            b0 = *(const float4*)(x + (size_t)(ko + bkr) * HWSZ + nT + bn4 * 4);
        }
        __syncthreads();
        short8 fa0 = *(short8*)&As[l4 * 1024 + (wm + l15) * 8];
        short8 fa1 = *(short8*)&As[l4 * 1024 + (wm + 16 + l15) * 8];
        short8 fb0 = *(short8*)&Bs[l4 * 256 + l15 * 8];
        short8 fb1 = *(short8*)&Bs[l4 * 256 + (16 + l15) * 8];
        acc[0][0] = __builtin_amdgcn_mfma_f32_16x16x32_bf16(fa0, fb0, acc[0][0], 0, 0, 0);
        acc[0][1] = __builtin_amdgcn_mfma_f32_16x16x32_bf16(fa0, fb1, acc[0][1], 0, 0, 0);
        acc[1][0] = __builtin_amdgcn_mfma_f32_16x16x32_bf16(fa1, fb0, acc[1][0], 0, 0, 0);
        acc[1][1] = __builtin_amdgcn_mfma_f32_16x16x32_bf16(fa1, fb1, acc[1][1], 0, 0, 0);
        __syncthreads();
    }
    // epilogue: C/D layout col=lane&15, row=(lane>>4)*4+reg
    const bool isK = (wid < 2);
    float*       Cd   = isK ? km : qm;
    const float* bias = isK ? bk : bq;
    const int rbase = (wm & 63);
    #pragma unroll
    for (int wm2 = 0; wm2 < 2; ++wm2)
        #pragma unroll
        for (int wn2 = 0; wn2 < 2; ++wn2)
            #pragma unroll
            for (int r = 0; r < 4; ++r) {
                int row = rbase + wm2 * 16 + l4 * 4 + r;
                int col = nT + wn2 * 16 + l15;
                Cd[(size_t)row * HWSZ + col] = acc[wm2][wn2][r] + bias[row];
            }
}

// ---------------- Kernel 3: fconv GEMM, 64x32 tiles, 896 blocks ----------
__global__ __launch_bounds__(256) void fconv_mfma(
    const float* __restrict__ pre,
    const float* __restrict__ Wf, const float* __restrict__ bfv,
    float* __restrict__ out)
{
    __shared__ unsigned short As[2048];   // 4 KB  [kg(4)][m(64)][j(8)]
    __shared__ unsigned short Bs[1024];   // 2 KB  [kg(4)][n(32)][j(8)]

    const int tid  = threadIdx.x;
    const int nT   = blockIdx.x * 32;
    const int oT   = blockIdx.y * 64;
    const int lane = tid & 63;
    const int wid  = tid >> 6;
    const int l15  = lane & 15;
    const int l4   = lane >> 4;

    const int ar = tid >> 3;          // 0..31
    const int ak = tid & 7;
    const int bkr = tid >> 3;
    const int bn4 = tid & 7;

    const float* __restrict__ A = Wf + (size_t)oT * CC;

    f32x4 acc[2];
    acc[0] = (f32x4){0.f, 0.f, 0.f, 0.f};
    acc[1] = (f32x4){0.f, 0.f, 0.f, 0.f};

    float4 a0 = *(const float4*)(A + (size_t)ar * CC + ak * 4);
    float4 a1 = *(const float4*)(A + (size_t)(ar + 32) * CC + ak * 4);
    float4 b0 = *(const float4*)(pre + (size_t)bkr * HWSZ + nT + bn4 * 4);

    for (int kt = 0; kt < 14; ++kt) {
        {
            int kg = ak >> 1, jo = (ak & 1) * 4;
            us4 w;
            w = (us4){ f2b(a0.x), f2b(a0.y), f2b(a0.z), f2b(a0.w) };
            *(us4*)&As[kg * 512 + (ar +  0) * 8 + jo] = w;
            w = (us4){ f2b(a1.x), f2b(a1.y), f2b(a1.z), f2b(a1.w) };
            *(us4*)&As[kg * 512 + (ar + 32) * 8 + jo] = w;
            int base = (bkr >> 3) * 256 + bn4 * 32 + (bkr & 7);
            Bs[base]      = f2b(b0.x);
            Bs[base + 8]  = f2b(b0.y);
            Bs[base + 16] = f2b(b0.z);
            Bs[base + 24] = f2b(b0.w);
        }
        if (kt < 13) {
            int ko = (kt + 1) * 32;
            a0 = *(const float4*)(A + (size_t)ar * CC + ko + ak * 4);
            a1 = *(const float4*)(A + (size_t)(ar + 32) * CC + ko + ak * 4);
            b0 = *(const float4*)(pre + (size_t)(ko + bkr) * HWSZ + nT + bn4 * 4);
        }
        __syncthreads();
        // wave w covers rows w*16 .. w*16+16 of the 64-row tile
        short8 fa  = *(short8*)&As[l4 * 512 + (wid * 16 + l15) * 8];
        short8 fb0 = *(short8*)&Bs[l4 * 256 + l15 * 8];
        short8 fb1 = *(short8*)&Bs[l4 * 256 + (16 + l15) * 8];
        acc[0] = __builtin_amdgcn_mfma_f32_16x16x32_bf16(fa, fb0, acc[0], 0, 0, 0);
        acc[1] = __builtin_amdgcn_mfma_f32_16x16x32_bf16(fa, fb1, acc[1], 0, 0, 0);
        __syncthreads();
    }
    #pragma unroll
    for (int wn2 = 0; wn2 < 2; ++wn2)
        #pragma unroll
        for (int r = 0; r < 4; ++r) {
            int row = oT + wid * 16 + l4 * 4 + r;
            int col = nT + wn2 * 16 + l15;
            out[(size_t)row * HWSZ + col] = acc[wn2][r] + bfv[row];
        }
}

// ---------------- Kernel 2: attention + aggregation (gpk fused) ----------
#define GLO 196
#define GHI 260
#define XWORDS (GLO + HWSZ + GHI)   // 4552 words

__device__ __forceinline__ int win_off_global(int n, bool& ok) {
    int p  = n >> 12;
    int l  = n & 4095;
    int di = (p * 37) >> 8;    // p/7 exact for 0..48
    int dj = p - di * 7;
    int i  = (l >> 6) + di - 3;
    int j  = (l & 63) + dj - 3;
    ok = ((unsigned)i < 64u) && ((unsigned)j < 64u);
    return i * 64 + j;
}

__global__ __launch_bounds__(256) void attn_kernel(
    const float* __restrict__ km, const float* __restrict__ qm,
    const float* __restrict__ x,
    const float* __restrict__ gw1, const float* __restrict__ gb1,
    const float* __restrict__ gw2, const float* __restrict__ gb2,
    float* __restrict__ pre)
{
    __shared__ float klin[XWORDS];
    __shared__ float xlin[XWORDS];
    __shared__ float gpk_s[KK2];
    const int tid = threadIdx.x;
    const int g   = blockIdx.y;
    const int lp  = blockIdx.x * 256 + tid;

    // zero guard bands: lo 49 float4, hi 65 float4 each
    if (tid < 114) {
        float4 z = {0.f, 0.f, 0.f, 0.f};
        int w = (tid < 49) ? tid * 4 : (GLO + HWSZ + (tid - 49) * 4);
        *(float4*)&klin[w] = z;
        *(float4*)&xlin[w] = z;
    }
    // stage km page: 256 threads x 4 float4
    {
        const float4* km4 = (const float4*)(km + (size_t)g * HWSZ);
        #pragma unroll
        for (int i = 0; i < 4; ++i) {
            int idx = tid + i * 256;
            *(float4*)&klin[GLO + idx * 4] = km4[idx];
        }
    }
    // fused geometry prior: row g (49 values)
    if (tid < KK2) {
        int di = tid / 7, dj = tid - di * 7;
        float xp = (float)(dj - 3);
        float yp = (float)(3 - di);
        float acc = gb2[g];
        #pragma unroll
        for (int j = 0; j < GPH; ++j) {
            float h = gw1[j * 2 + 0] * xp + gw1[j * 2 + 1] * yp + gb1[j];
            h = fmaxf(h, 0.f);
            acc = fmaf(gw2[g * GPH + j], h, acc);
        }
        gpk_s[tid] = acc;
    }

    // q center
    float qc;
    { bool ok; int o = win_off_global(lp * KK2 + 24, ok); qc = ok ? qm[(size_t)g * HWSZ + o] : 0.f; }

    // per-thread segment constants (taps contiguous in <=2 segments)
    const int n0 = lp * KK2;
    const int p0 = n0 >> 12;
    const int l0 = n0 & 4095;
    const int ts = ((p0 + 1) << 12) - n0;
    const int di0 = (p0 * 37) >> 8, dj0 = p0 - di0 * 7;
    const int p1  = p0 + 1;
    const int di1 = (p1 * 37) >> 8, dj1 = p1 - di1 * 7;
    const int djm3_0 = dj0 - 3, djm3_1 = dj1 - 3;
    const int B0 = GLO + l0 + (di0 - 3) * 64 + djm3_0;
    const int B1 = GLO + l0 - 4096 + (di1 - 3) * 64 + djm3_1;

    // prologue: m=0 x page into registers (overlaps phase A)
    float4 xr0, xr1, xr2, xr3;
    {
        const float4* xg4 = (const float4*)(x + (size_t)g * HWSZ);
        xr0 = xg4[tid]; xr1 = xg4[tid + 256]; xr2 = xg4[tid + 512]; xr3 = xg4[tid + 768];
    }
    __syncthreads();   // klin/guards/gpk staged

    // Phase A: logits
    float a[KK2];
    float mx = -1e30f;
    #pragma unroll
    for (int t = 0; t < KK2; ++t) {
        bool s1 = (t >= ts);
        int base = s1 ? B1 : B0;
        float kv = klin[base + t];
        int jj = ((l0 + t) & 63) + (s1 ? djm3_1 : djm3_0);
        kv = ((unsigned)jj < 64u) ? kv : 0.f;
        float av = fmaf(kv, qc, gpk_s[t]);
        a[t] = av;
        mx = fmaxf(mx, av);
    }
    float d = 0.f;
    #pragma unroll
    for (int t = 0; t < KK2; ++t) {
        float e = __expf(a[t] - mx);
        d += e;                                  // padded taps count in denominator
        bool s1 = (t >= ts);
        int jj = ((l0 + t) & 63) + (s1 ? djm3_1 : djm3_0);
        a[t] = ((unsigned)jj < 64u) ? e : 0.f;
    }
    const float inv = 1.f / d;

    // Phase B: per m, write staged page, prefetch next, accumulate
    #pragma unroll 1
    for (int m = 0; m < MMM; ++m) {
        __syncthreads();   // prior readers of xlin done
        *(float4*)&xlin[GLO + tid * 4]          = xr0;
        *(float4*)&xlin[GLO + (tid + 256) * 4]  = xr1;
        *(float4*)&xlin[GLO + (tid + 512) * 4]  = xr2;
        *(float4*)&xlin[GLO + (tid + 768) * 4]  = xr3;
        if (m < MMM - 1) {
            const float4* xg4 = (const float4*)(x + (size_t)((m + 1) * CGC + g) * HWSZ);
            xr0 = xg4[tid]; xr1 = xg4[tid + 256]; xr2 = xg4[tid + 512]; xr3 = xg4[tid + 768];
        }
        __syncthreads();
        float acc = 0.f;
        #pragma unroll
        for (int t = 0; t < KK2; ++t) {
            int base = (t >= ts) ? B1 : B0;
            acc = fmaf(a[t], xlin[base + t], acc);
        }
        pre[(size_t)(m * CGC + g) * HWSZ + lp] = acc * inv;
    }
}

extern "C" void kernel_launch(void* const* d_in, const int* in_sizes, int n_in,
                              void* d_out, int out_size, void* d_ws, size_t ws_size,
                              hipStream_t stream) {
    const float* x   = (const float*)d_in[0];
    const float* Wk  = (const float*)d_in[1];
    const float* bk  = (const float*)d_in[2];
    const float* Wq  = (const float*)d_in[3];
    const float* bq  = (const float*)d_in[4];
    const float* gw1 = (const float*)d_in[5];
    const float* gb1 = (const float*)d_in[6];
    const float* gw2 = (const float*)d_in[7];
    const float* gb2 = (const float*)d_in[8];
    const float* Wf  = (const float*)d_in[9];
    const float* bfv = (const float*)d_in[10];
    float* out = (float*)d_out;

    float* km  = (float*)d_ws;             // 64*4096
    float* qm  = km + CGC * HWSZ;          // 64*4096
    float* pre = qm + CGC * HWSZ;          // 448*4096

    kq_mfma    <<<dim3(128),     256, 0, stream>>>(x, Wk, bk, Wq, bq, km, qm);
    attn_kernel<<<dim3(16, CGC), 256, 0, stream>>>(km, qm, x, gw1, gb1, gw2, gb2, pre);
    fconv_mfma <<<dim3(128, 7),  256, 0, stream>>>(pre, Wf, bfv, out);
}